// Round 7
// baseline (74.300 us; speedup 1.0000x reference)
//
#include <hip/hip_runtime.h>

// JetECF, beta=2. Established facts (R0-R6):
//  - Output fp32 in memory; harness bf16-rounds both sides before absmax.
//    Threshold = 3.62 bf16 ulps at max scale; R4-R6 achieved 1 ulp. PASS.
//  - ecf2 must replicate numpy's fp32 op order BIT-EXACTLY (immutable):
//      s_j  = sum_{i<j} fl( fl(fl((e_i-e_j)^2) + fl((p_i-p_j)^2)) * pt_i ),
//             sequential ascending i, single fp32 accumulator;
//      ecf2 = sum_j fl(pt_j * s_j), sequential ascending j, single fp32 acc.
//  - ecf1/ecf3 via exact fp64 rank-4 moment identity.
//  - Timing: harness floor ~64.7 us (d_ws poison fill 40 us + reset
//    dispatches); R6 kernel ~8.7 us, VALU-issue-bound.
//
// R7 change: pack independent column-set bodies into <2 x float> ops so the
// backend emits v_pk_{add,mul}_f32 (VOP3P, gfx90a+; MI355X's 157.3 TF fp32
// peak presumes packed). Per-half pk arithmetic is IEEE RNE per 32-bit half
// == scalar __f*_rn stream, and fp contract(off) forbids mul+add fusion, so
// every column accumulator sees the identical op sequence. Dead/masked
// halves add +0.0f (bitwise-neutral; accumulators are never -0).

constexpr int NPART = 200;

typedef float v2f __attribute__((ext_vector_type(2)));

__device__ __forceinline__ float bcast(float v, int ii) {
    return __int_as_float(__builtin_amdgcn_readlane(__float_as_int(v), ii));
}

__global__ __launch_bounds__(64) void jet_ecf_kernel(const float* __restrict__ x,
                                                     float* __restrict__ out,
                                                     int njet) {
#pragma clang fp contract(off)
    const int jet = blockIdx.x;
    if (jet >= njet) return;
    const int lane = threadIdx.x;
    const float* xj = x + (size_t)jet * NPART * 3;

    // Per-lane column cache: slot k = column 64k + lane.
    float pw[4], pe[4], pp[4];
    #pragma unroll
    for (int k = 0; k < 4; ++k) {
        const int p = 64 * k + lane;
        if (p < NPART) {
            pw[k] = xj[p * 3 + 0];
            pe[k] = xj[p * 3 + 1];
            pp[k] = xj[p * 3 + 2];
        } else {
            pw[k] = 0.0f; pe[k] = 0.0f; pp[k] = 0.0f;
        }
    }

    // ---- Phase A: exact fp64 moments (ecf1, ecf3). ----
    double S = 0, Sa = 0, Se = 0, Sp = 0, Saa = 0;
    double Sae = 0, Sap = 0, See = 0, Spp = 0, Sep = 0;
    #pragma unroll
    for (int k = 0; k < 4; ++k) {
        const double w = (double)pw[k];
        const double e = (double)pe[k];
        const double f = (double)pp[k];
        const double a = e * e + f * f;
        S   += w;        Sa  += w * a;     Se  += w * e;
        Sp  += w * f;    Saa += w * a * a; Sae += w * a * e;
        Sap += w * a * f; See += w * e * e; Spp += w * f * f;
        Sep += w * e * f;
    }
    #pragma unroll
    for (int off = 32; off > 0; off >>= 1) {
        S   += __shfl_down(S,   off, 64);
        Sa  += __shfl_down(Sa,  off, 64);
        Se  += __shfl_down(Se,  off, 64);
        Sp  += __shfl_down(Sp,  off, 64);
        Saa += __shfl_down(Saa, off, 64);
        Sae += __shfl_down(Sae, off, 64);
        Sap += __shfl_down(Sap, off, 64);
        See += __shfl_down(See, off, 64);
        Spp += __shfl_down(Spp, off, 64);
        Sep += __shfl_down(Sep, off, 64);
    }

    // ---- Phase B: np-order fp32 column sums, packed pairs (0,1) & (2,3).
    // i sweeps ascending (wave-uniform, scalar loads). In segment m the set
    // k == m is predicated by (ii < lane); sets k < m add +0.0f. ----
    const v2f pe01 = { pe[0], pe[1] }, pe23 = { pe[2], pe[3] };
    const v2f pp01 = { pp[0], pp[1] }, pp23 = { pp[2], pp[3] };
    v2f s01 = { 0.0f, 0.0f }, s23 = { 0.0f, 0.0f };

    // pk body, both halves live (unpredicated):
#define PK_BODY(ACC, PE, PP)                                                  \
    {                                                                         \
        const v2f dev = eiv - (PE);                                           \
        const v2f dpv = piv - (PP);                                           \
        const v2f m1 = dev * dev;                                             \
        const v2f m2 = dpv * dpv;                                             \
        const v2f r2 = m1 + m2;                                               \
        const v2f c  = r2 * wiv;                                              \
        ACC += c;                                                             \
    }
    // pk body, x-half predicated by (ii < lane):
#define PK_BODY_PX(ACC, PE, PP)                                               \
    {                                                                         \
        const v2f dev = eiv - (PE);                                           \
        const v2f dpv = piv - (PP);                                           \
        const v2f m1 = dev * dev;                                             \
        const v2f m2 = dpv * dpv;                                             \
        const v2f r2 = m1 + m2;                                               \
        v2f c  = r2 * wiv;                                                    \
        c.x = (ii < lane) ? c.x : 0.0f;                                       \
        ACC += c;                                                             \
    }
    // scalar body, predicated:
#define SC_BODY_PRED(ACC, K)                                                  \
    {                                                                         \
        const float de = __fsub_rn(ei, pe[K]);                                \
        const float dp = __fsub_rn(pi, pp[K]);                                \
        const float r2 = __fadd_rn(__fmul_rn(de, de), __fmul_rn(dp, dp));     \
        const float c  = __fmul_rn(r2, wi);                                   \
        ACC = __fadd_rn(ACC, (ii < lane) ? c : 0.0f);                         \
    }

    // Segment 0: i = ii in [0,64). Sets 0(pred),1,2,3.
    #pragma unroll 4
    for (int ii = 0; ii < 64; ++ii) {
        const float wi = xj[3 * ii + 0];
        const float ei = xj[3 * ii + 1];
        const float pi = xj[3 * ii + 2];
        const v2f wiv = { wi, wi }, eiv = { ei, ei }, piv = { pi, pi };
        PK_BODY_PX(s01, pe01, pp01)
        PK_BODY(s23, pe23, pp23)
    }
    // Segment 1: i = 64 + ii. Sets 1(pred, scalar), 2, 3 (pk).
    #pragma unroll 4
    for (int ii = 0; ii < 64; ++ii) {
        const float wi = xj[3 * (64 + ii) + 0];
        const float ei = xj[3 * (64 + ii) + 1];
        const float pi = xj[3 * (64 + ii) + 2];
        const v2f wiv = { wi, wi }, eiv = { ei, ei }, piv = { pi, pi };
        float s1 = s01.y;
        SC_BODY_PRED(s1, 1)
        s01.y = s1;
        PK_BODY(s23, pe23, pp23)
    }
    // Segment 2: i = 128 + ii. Sets 2(pred), 3 as one pk pair.
    #pragma unroll 4
    for (int ii = 0; ii < 64; ++ii) {
        const float wi = xj[3 * (128 + ii) + 0];
        const float ei = xj[3 * (128 + ii) + 1];
        const float pi = xj[3 * (128 + ii) + 2];
        const v2f wiv = { wi, wi }, eiv = { ei, ei }, piv = { pi, pi };
        PK_BODY_PX(s23, pe23, pp23)
    }
    // Segment 3: i = 192 + ii, ii in [0,7). Set 3 (pred, scalar).
    #pragma unroll
    for (int ii = 0; ii < 7; ++ii) {
        const float wi = xj[3 * (192 + ii) + 0];
        const float ei = xj[3 * (192 + ii) + 1];
        const float pi = xj[3 * (192 + ii) + 2];
        float s3 = s23.y;
        SC_BODY_PRED(s3, 3)
        s23.y = s3;
    }
#undef PK_BODY
#undef PK_BODY_PX
#undef SC_BODY_PRED

    // t_j = fl(pt_j * s_j)
    const float t0 = __fmul_rn(pw[0], s01.x);
    const float t1 = __fmul_rn(pw[1], s01.y);
    const float t2 = __fmul_rn(pw[2], s23.x);
    const float t3 = __fmul_rn(pw[3], s23.y);

    // Final np step: ecf2 = sum_j fl(pt_j*s_j), sequential ascending j.
    float e2f = 0.0f;
    #pragma unroll 8
    for (int ii = 0; ii < 64; ++ii) e2f = __fadd_rn(e2f, bcast(t0, ii));
    #pragma unroll 8
    for (int ii = 0; ii < 64; ++ii) e2f = __fadd_rn(e2f, bcast(t1, ii));
    #pragma unroll 8
    for (int ii = 0; ii < 64; ++ii) e2f = __fadd_rn(e2f, bcast(t2, ii));
    #pragma unroll
    for (int ii = 0; ii < 8; ++ii)  e2f = __fadd_rn(e2f, bcast(t3, ii));

    if (lane == 0) {
        // ecf3 = (1/6) sum A[al][be] B[al][ga] C[be][ga];
        // A = m(u,u), B = m(v,u), C = m(v,v); u = {a,1,-2e,-2p}, v = {1,a,e,p}.
        const double A[4][4] = {
            {  Saa,        Sa,       -2.0 * Sae, -2.0 * Sap },
            {  Sa,         S,        -2.0 * Se,  -2.0 * Sp  },
            { -2.0 * Sae, -2.0 * Se,  4.0 * See,  4.0 * Sep },
            { -2.0 * Sap, -2.0 * Sp,  4.0 * Sep,  4.0 * Spp }
        };
        const double B[4][4] = {
            { Sa,  S,  -2.0 * Se,  -2.0 * Sp  },
            { Saa, Sa, -2.0 * Sae, -2.0 * Sap },
            { Sae, Se, -2.0 * See, -2.0 * Sep },
            { Sap, Sp, -2.0 * Sep, -2.0 * Spp }
        };
        const double C[4][4] = {
            { S,  Sa,  Se,  Sp  },
            { Sa, Saa, Sae, Sap },
            { Se, Sae, See, Sep },
            { Sp, Sap, Sep, Spp }
        };
        double T = 0.0;
        #pragma unroll
        for (int b = 0; b < 4; ++b) {
            #pragma unroll
            for (int g = 0; g < 4; ++g) {
                double ab = 0.0;
                #pragma unroll
                for (int al = 0; al < 4; ++al) ab += A[al][b] * B[al][g];
                T += ab * C[b][g];
            }
        }
        const double ecf1 = S;
        const double ecf2 = (double)e2f;   // np's fp32 value
        const double ecf3 = T * (1.0 / 6.0);
        const double d2 = ecf3 * ecf1 * ecf1 * ecf1 / (ecf2 * ecf2 * ecf2 + 1e-7);
        float4 o = make_float4((float)ecf1, (float)ecf2, (float)ecf3, (float)d2);
        *reinterpret_cast<float4*>(out + (size_t)jet * 4) = o;
    }
}

extern "C" void kernel_launch(void* const* d_in, const int* in_sizes, int n_in,
                              void* d_out, int out_size, void* d_ws, size_t ws_size,
                              hipStream_t stream) {
    const float* x = (const float*)d_in[0];
    float* out = (float*)d_out;
    const int njet = in_sizes[0] / (NPART * 3);
    jet_ecf_kernel<<<njet, 64, 0, stream>>>(x, out, njet);
}

// Round 8
// 73.293 us; speedup vs baseline: 1.0137x; 1.0137x over previous
//
#include <hip/hip_runtime.h>

// JetECF, beta=2. Established facts (R0-R7):
//  - Output fp32 in memory; harness bf16-rounds both sides before absmax.
//    Threshold = 3.62 bf16 ulps at max scale; R4-R7 achieved 1 ulp. PASS.
//  - ecf2 must replicate numpy's fp32 op order BIT-EXACTLY (immutable):
//      s_j  = sum_{i<j} fl( fl(fl((e_i-e_j)^2) + fl((p_i-p_j)^2)) * pt_i ),
//             sequential ascending i, single fp32 accumulator;
//      ecf2 = sum_j fl(pt_j * s_j), sequential ascending j, single fp32 acc.
//  - ecf1/ecf3 via exact fp64 rank-4 moment identity (np-noise there is far
//    inside one bf16 bucket).
//  - Timing: harness floor ~64.7 us (40 us d_ws poison fill + reset
//    dispatches); kernel ~8.7 us, VALU-issue-bound. R7's <2 x float> pk
//    attempt was neutral: ISel scalarizes, no v_pk_*_f32 emitted.
//
// R8 change: column->slot regrouping to minimize issued slot-bodies.
// Slot k participates for all i < max_j(slot k), so Sum_k max_j is the issue
// cost. Old grouping [0-63][64-127][128-191][192-199]: 583 slot-steps.
// New grouping [0-7][8-71][72-135][136-199]: 7+71+135+199 = 412 (-29%).
// Each column's fl-op sequence is unchanged (ascending i, one fp32 acc).

constexpr int NPART = 200;

__device__ __forceinline__ float bcast(float v, int ii) {
    return __int_as_float(__builtin_amdgcn_readlane(__float_as_int(v), ii));
}

__global__ __launch_bounds__(64) void jet_ecf_kernel(const float* __restrict__ x,
                                                     float* __restrict__ out,
                                                     int njet) {
#pragma clang fp contract(off)
    const int jet = blockIdx.x;
    if (jet >= njet) return;
    const int lane = threadIdx.x;
    const float* xj = x + (size_t)jet * NPART * 3;

    // Column mapping: slot0: j = lane (lanes 0..7 only), slot1: j = 8+lane,
    // slot2: j = 72+lane, slot3: j = 136+lane. Dummy lanes zero-padded
    // (their accumulators are garbage-but-unread; t = 0*s = 0 anyway).
    float pw[4], pe[4], pp[4];
    {
        const int base[4] = { 0, 8, 72, 136 };
        #pragma unroll
        for (int k = 0; k < 4; ++k) {
            const int p = base[k] + lane;
            const bool valid = (k > 0) || (lane < 8);
            if (valid) {
                pw[k] = xj[p * 3 + 0];
                pe[k] = xj[p * 3 + 1];
                pp[k] = xj[p * 3 + 2];
            } else {
                pw[k] = 0.0f; pe[k] = 0.0f; pp[k] = 0.0f;
            }
        }
    }

    // ---- Phase A: exact fp64 moments (ecf1, ecf3). Zero-padded slots
    // contribute exactly 0; slots 0..3 cover each particle exactly once. ----
    double S = 0, Sa = 0, Se = 0, Sp = 0, Saa = 0;
    double Sae = 0, Sap = 0, See = 0, Spp = 0, Sep = 0;
    #pragma unroll
    for (int k = 0; k < 4; ++k) {
        const double w = (double)pw[k];
        const double e = (double)pe[k];
        const double f = (double)pp[k];
        const double a = e * e + f * f;
        S   += w;        Sa  += w * a;     Se  += w * e;
        Sp  += w * f;    Saa += w * a * a; Sae += w * a * e;
        Sap += w * a * f; See += w * e * e; Spp += w * f * f;
        Sep += w * e * f;
    }
    #pragma unroll
    for (int off = 32; off > 0; off >>= 1) {
        S   += __shfl_down(S,   off, 64);
        Sa  += __shfl_down(Sa,  off, 64);
        Se  += __shfl_down(Se,  off, 64);
        Sp  += __shfl_down(Sp,  off, 64);
        Saa += __shfl_down(Saa, off, 64);
        Sae += __shfl_down(Sae, off, 64);
        Sap += __shfl_down(Sap, off, 64);
        See += __shfl_down(See, off, 64);
        Spp += __shfl_down(Spp, off, 64);
        Sep += __shfl_down(Sep, off, 64);
    }

    // ---- Phase B: np-order fp32 column sums. Slot k live for i < max_j(k);
    // within a slot, steps i >= base predicated by (ii < lane) where
    // ii = i - base (j = base + lane). i-side values are wave-uniform scalar
    // loads. Masked lanes add +0.0f (bit-exact; accs never -0). ----
    float s0 = 0.0f, s1 = 0.0f, s2 = 0.0f, s3 = 0.0f;

#define BODY(ACC, K)                                                          \
    {                                                                         \
        const float de = __fsub_rn(ei, pe[K]);                                \
        const float dp = __fsub_rn(pi, pp[K]);                                \
        const float r2 = __fadd_rn(__fmul_rn(de, de), __fmul_rn(dp, dp));     \
        ACC = __fadd_rn(ACC, __fmul_rn(r2, wi));                              \
    }
#define BODY_PRED(ACC, K)                                                     \
    {                                                                         \
        const float de = __fsub_rn(ei, pe[K]);                                \
        const float dp = __fsub_rn(pi, pp[K]);                                \
        const float r2 = __fadd_rn(__fmul_rn(de, de), __fmul_rn(dp, dp));     \
        const float c  = __fmul_rn(r2, wi);                                   \
        ACC = __fadd_rn(ACC, (ii < lane) ? c : 0.0f);                         \
    }
#define LOAD_I(I)                                                             \
    const float wi = xj[3 * (I) + 0];                                         \
    const float ei = xj[3 * (I) + 1];                                         \
    const float pi = xj[3 * (I) + 2];

    // Seg A: i = 0..6 — slot0 pred, slots 1,2,3 unpred (i < 8 <= their base).
    #pragma unroll
    for (int ii = 0; ii < 7; ++ii) {
        LOAD_I(ii)
        BODY_PRED(s0, 0)
        BODY(s1, 1)
        BODY(s2, 2)
        BODY(s3, 3)
    }
    // Seg B: i = 7 — slots 1,2,3 unpred (slot0's max j = 7 needs i <= 6).
    {
        const int ii = 7;
        LOAD_I(ii)
        BODY(s1, 1)
        BODY(s2, 2)
        BODY(s3, 3)
    }
    // Seg C: i = 8..70 (ii = i-8) — slot1 pred (i < 8+lane <=> ii < lane),
    // slots 2,3 unpred.
    #pragma unroll 4
    for (int ii = 0; ii < 63; ++ii) {
        LOAD_I(8 + ii)
        BODY_PRED(s1, 1)
        BODY(s2, 2)
        BODY(s3, 3)
    }
    // Seg D: i = 71 — slots 2,3 unpred (slot1 max j = 71 needs i <= 70).
    {
        const int ii = 71;
        LOAD_I(ii)
        BODY(s2, 2)
        BODY(s3, 3)
    }
    // Seg E: i = 72..134 (ii = i-72) — slot2 pred, slot3 unpred.
    #pragma unroll 4
    for (int ii = 0; ii < 63; ++ii) {
        LOAD_I(72 + ii)
        BODY_PRED(s2, 2)
        BODY(s3, 3)
    }
    // Seg F: i = 135 — slot3 unpred (slot2 max j = 135 needs i <= 134).
    {
        const int ii = 135;
        LOAD_I(ii)
        BODY(s3, 3)
    }
    // Seg G: i = 136..198 (ii = i-136) — slot3 pred.
    #pragma unroll 4
    for (int ii = 0; ii < 63; ++ii) {
        LOAD_I(136 + ii)
        BODY_PRED(s3, 3)
    }
#undef BODY
#undef BODY_PRED
#undef LOAD_I

    // t_j = fl(pt_j * s_j)
    const float t0 = __fmul_rn(pw[0], s0);
    const float t1 = __fmul_rn(pw[1], s1);
    const float t2 = __fmul_rn(pw[2], s2);
    const float t3 = __fmul_rn(pw[3], s3);

    // Final np step: ecf2 = sum_j fl(pt_j*s_j), sequential ascending j:
    // j = 0..7 (slot0 lanes 0..7), 8..71 (slot1), 72..135 (slot2),
    // 136..199 (slot3).
    float e2f = 0.0f;
    #pragma unroll
    for (int ii = 0; ii < 8; ++ii)  e2f = __fadd_rn(e2f, bcast(t0, ii));
    #pragma unroll 8
    for (int ii = 0; ii < 64; ++ii) e2f = __fadd_rn(e2f, bcast(t1, ii));
    #pragma unroll 8
    for (int ii = 0; ii < 64; ++ii) e2f = __fadd_rn(e2f, bcast(t2, ii));
    #pragma unroll 8
    for (int ii = 0; ii < 64; ++ii) e2f = __fadd_rn(e2f, bcast(t3, ii));

    if (lane == 0) {
        // ecf3 = (1/6) sum A[al][be] B[al][ga] C[be][ga];
        // A = m(u,u), B = m(v,u), C = m(v,v); u = {a,1,-2e,-2p}, v = {1,a,e,p}.
        const double A[4][4] = {
            {  Saa,        Sa,       -2.0 * Sae, -2.0 * Sap },
            {  Sa,         S,        -2.0 * Se,  -2.0 * Sp  },
            { -2.0 * Sae, -2.0 * Se,  4.0 * See,  4.0 * Sep },
            { -2.0 * Sap, -2.0 * Sp,  4.0 * Sep,  4.0 * Spp }
        };
        const double B[4][4] = {
            { Sa,  S,  -2.0 * Se,  -2.0 * Sp  },
            { Saa, Sa, -2.0 * Sae, -2.0 * Sap },
            { Sae, Se, -2.0 * See, -2.0 * Sep },
            { Sap, Sp, -2.0 * Sep, -2.0 * Spp }
        };
        const double C[4][4] = {
            { S,  Sa,  Se,  Sp  },
            { Sa, Saa, Sae, Sap },
            { Se, Sae, See, Sep },
            { Sp, Sap, Sep, Spp }
        };
        double T = 0.0;
        #pragma unroll
        for (int b = 0; b < 4; ++b) {
            #pragma unroll
            for (int g = 0; g < 4; ++g) {
                double ab = 0.0;
                #pragma unroll
                for (int al = 0; al < 4; ++al) ab += A[al][b] * B[al][g];
                T += ab * C[b][g];
            }
        }
        const double ecf1 = S;
        const double ecf2 = (double)e2f;   // np's fp32 value
        const double ecf3 = T * (1.0 / 6.0);
        const double d2 = ecf3 * ecf1 * ecf1 * ecf1 / (ecf2 * ecf2 * ecf2 + 1e-7);
        float4 o = make_float4((float)ecf1, (float)ecf2, (float)ecf3, (float)d2);
        *reinterpret_cast<float4*>(out + (size_t)jet * 4) = o;
    }
}

extern "C" void kernel_launch(void* const* d_in, const int* in_sizes, int n_in,
                              void* d_out, int out_size, void* d_ws, size_t ws_size,
                              hipStream_t stream) {
    const float* x = (const float*)d_in[0];
    float* out = (float*)d_out;
    const int njet = in_sizes[0] / (NPART * 3);
    jet_ecf_kernel<<<njet, 64, 0, stream>>>(x, out, njet);
}